// Round 13
// baseline (1176.223 us; speedup 1.0000x reference)
//
#include <hip/hip_runtime.h>

#define NN 100000
#define EE 1600000
#define DIN 128
#define DH 64
#define DOUT 32

#define BSH 8                      // bucket = dst >> 8  (256 nodes/bucket)
#define BNODES 256
#define NBUCK ((NN + BNODES - 1) / BNODES)   // 391
#define BCAP 4608                  // fixed bucket capacity (mean 4096 + 8 sigma)
#define CHUNK 4096                 // edges per Pass-A workgroup
#define NCHUNK ((EE + CHUNK - 1) / CHUNK)    // 391

typedef unsigned short ush;
typedef __attribute__((ext_vector_type(8))) short bf16x8;
typedef __attribute__((ext_vector_type(4))) float f32x4;

__device__ __forceinline__ float bflo(unsigned u) {
    union { unsigned u; float f; } c; c.u = u << 16; return c.f;
}
__device__ __forceinline__ float bfhi(unsigned u) {
    union { unsigned u; float f; } c; c.u = u & 0xffff0000u; return c.f;
}
__device__ __forceinline__ float bf2f(ush u) {
    union { unsigned u; float f; } c; c.u = ((unsigned)u) << 16; return c.f;
}
__device__ __forceinline__ ush f2bf(float f) {
    union { float f; unsigned u; } c; c.f = f;
    unsigned r = c.u + 0x7fff + ((c.u >> 16) & 1);   // round-to-nearest-even
    return (ush)(r >> 16);
}

// ---------------- init bucket cursors to fixed bases ----------------
__global__ void init_bcur_kernel(int* __restrict__ bcur) {
    int i = blockIdx.x * 256 + threadIdx.x;
    if (i < NBUCK) bcur[i] = i * BCAP;
}

// ---------------- Pass A: bin edges into fixed-capacity buckets (packed (src<<8)|dstlow)
__global__ __launch_bounds__(256) void binA_kernel(const int* __restrict__ src,
                                                   const int* __restrict__ dst,
                                                   int* __restrict__ bcur,
                                                   unsigned* __restrict__ tmp) {
    __shared__ int hist[NBUCK];
    __shared__ int scn[NBUCK];      // exclusive scan (staging base per bucket)
    __shared__ int cur[NBUCK];      // staging cursor
    __shared__ int gb[NBUCK];       // global base - scn  (addr = gb[b] + lp)
    __shared__ int s2[256];
    __shared__ unsigned staged[CHUNK];
    __shared__ int gaddr[CHUNK];
    int t = threadIdx.x;
    for (int i = t; i < NBUCK; i += 256) hist[i] = 0;
    __syncthreads();
    int e0 = blockIdx.x * CHUNK;
    int nE = min(CHUNK, EE - e0);

    int my_e[16], my_bk[16];
#pragma unroll
    for (int k = 0; k < 16; k++) {
        int li = t + k * 256;
        bool ok = li < nE;
        int idx = ok ? (e0 + li) : e0;
        int d = dst[idx];
        int s = src[idx];
        int b = d >> BSH;
        my_e[k] = (s << 8) | (d & 255);
        my_bk[k] = ok ? b : -1;
        if (ok) atomicAdd(&hist[b], 1);
    }
    __syncthreads();
    int a0 = (2 * t < NBUCK) ? hist[2 * t] : 0;
    int a1 = (2 * t + 1 < NBUCK) ? hist[2 * t + 1] : 0;
    s2[t] = a0 + a1;
    __syncthreads();
    for (int off = 1; off < 256; off <<= 1) {
        int x = (t >= off) ? s2[t - off] : 0;
        __syncthreads();
        s2[t] += x;
        __syncthreads();
    }
    int excl = s2[t] - a0 - a1;
    if (2 * t < NBUCK)     { scn[2 * t] = excl;          cur[2 * t] = excl; }
    if (2 * t + 1 < NBUCK) { scn[2 * t + 1] = excl + a0; cur[2 * t + 1] = excl + a0; }
    __syncthreads();
    for (int i = t; i < NBUCK; i += 256) {
        int h = hist[i];
        if (h) gb[i] = atomicAdd(&bcur[i], h) - scn[i];
    }
    __syncthreads();
#pragma unroll
    for (int k = 0; k < 16; k++) {
        int b = my_bk[k];
        if (b >= 0) {
            int lp = atomicAdd(&cur[b], 1);
            staged[lp] = (unsigned)my_e[k];
            gaddr[lp] = gb[b] + lp;
        }
    }
    __syncthreads();
    for (int i = t; i < nE; i += 256)
        tmp[gaddr[i]] = staged[i];
}

// ---------------- Pass C: per-bucket node degree -> dinv (no csr needed) ---------------
__global__ __launch_bounds__(256) void binC_kernel(const unsigned* __restrict__ tmp,
                                                   const int* __restrict__ bcur,
                                                   float* __restrict__ dinv) {
    __shared__ int h[BNODES];
    int b = blockIdx.x, t = threadIdx.x;
    int e0 = b * BCAP, e1 = bcur[b];
    h[t] = 0;
    __syncthreads();
    for (int i = e0 + t; i < e1; i += 256) atomicAdd(&h[tmp[i] & 255], 1);
    __syncthreads();
    int node = (b << BSH) + t;
    if (node < NN) dinv[node] = 1.0f / sqrtf((float)h[t] + 1.0f);
}

// ---------------- MFMA GEMM + dinv-scale, bf16 out: Y = bf16((X@W)*dinv) -------------
template <int K, int NC, typename XT>
__global__ __launch_bounds__(256) void gemm_mfma_kernel(const XT* __restrict__ X,
                                                        const float* __restrict__ W,
                                                        const float* __restrict__ dinv,
                                                        ush* __restrict__ Y) {
    constexpr int GROWS = 128;
    constexpr int KP = K + 8;            // pad: row stride odd multiple of 16B
    constexpr int NKC = K / 32;          // k-chunks
    constexpr int NCT = NC / 16;         // col tiles
    __shared__ __align__(16) ush Xl[GROWS * KP];
    __shared__ __align__(16) ush Wt[NC * KP];
    const int t = threadIdx.x;
    const int row0 = blockIdx.x * GROWS;

    if constexpr (sizeof(XT) == 4) {
        for (int i = t; i < GROWS * (K / 4); i += 256) {
            int r = i / (K / 4), c4 = i % (K / 4);
            int row = row0 + r;
            float4 v = make_float4(0.f, 0.f, 0.f, 0.f);
            if (row < NN) v = *(const float4*)&X[(size_t)row * K + c4 * 4];
            ushort4 o;
            o.x = f2bf(v.x); o.y = f2bf(v.y); o.z = f2bf(v.z); o.w = f2bf(v.w);
            *(ushort4*)&Xl[r * KP + c4 * 4] = o;
        }
    } else {
        for (int i = t; i < GROWS * (K / 8); i += 256) {
            int r = i / (K / 8), c8 = i % (K / 8);
            int row = row0 + r;
            uint4 v = make_uint4(0, 0, 0, 0);
            if (row < NN) v = *(const uint4*)&X[(size_t)row * K + c8 * 8];
            *(uint4*)&Xl[r * KP + c8 * 8] = v;
        }
    }
    for (int i = t; i < K * (NC / 4); i += 256) {
        int k = i / (NC / 4), n4 = i % (NC / 4);
        float4 v = *(const float4*)&W[k * NC + n4 * 4];
        Wt[(n4 * 4 + 0) * KP + k] = f2bf(v.x);
        Wt[(n4 * 4 + 1) * KP + k] = f2bf(v.y);
        Wt[(n4 * 4 + 2) * KP + k] = f2bf(v.z);
        Wt[(n4 * 4 + 3) * KP + k] = f2bf(v.w);
    }
    __syncthreads();

    const int wave = t >> 6, lane = t & 63;
    const int m = lane & 15, quad = lane >> 4;
    const int wrow = wave * 32;

    f32x4 acc[2][NCT];
#pragma unroll
    for (int rt = 0; rt < 2; rt++)
#pragma unroll
        for (int ct = 0; ct < NCT; ct++) acc[rt][ct] = (f32x4){0.f, 0.f, 0.f, 0.f};

#pragma unroll
    for (int kc = 0; kc < NKC; kc++) {
        int koff = kc * 32 + quad * 8;
        bf16x8 b[NCT];
#pragma unroll
        for (int ct = 0; ct < NCT; ct++)
            b[ct] = *(const bf16x8*)&Wt[(ct * 16 + m) * KP + koff];
#pragma unroll
        for (int rt = 0; rt < 2; rt++) {
            bf16x8 a = *(const bf16x8*)&Xl[(wrow + rt * 16 + m) * KP + koff];
#pragma unroll
            for (int ct = 0; ct < NCT; ct++)
                acc[rt][ct] = __builtin_amdgcn_mfma_f32_16x16x32_bf16(a, b[ct], acc[rt][ct], 0, 0, 0);
        }
    }
#pragma unroll
    for (int rt = 0; rt < 2; rt++) {
#pragma unroll
        for (int reg = 0; reg < 4; reg++) {
            int row = row0 + wrow + rt * 16 + quad * 4 + reg;
            if (row < NN) {
                float s = dinv[row];
#pragma unroll
                for (int ct = 0; ct < NCT; ct++)
                    Y[(size_t)row * NC + ct * 16 + m] = f2bf(acc[rt][ct][reg] * s);
            }
        }
    }
}

// ---------------- scat1: block-per-bucket LDS scatter, F=64 ----------------------------
// acc[dl][f] += Hs1[src][f] for every bucket edge; finish: h1 = bf16(relu(dv*(acc+self)+b1))
#define S1 65   // acc row stride (floats): spreads dl across banks
__global__ __launch_bounds__(512) void scat1_kernel(const unsigned* __restrict__ tmp,
                                                    const int* __restrict__ bcur,
                                                    const float* __restrict__ dinv,
                                                    const ush* __restrict__ Hs,
                                                    const float* __restrict__ b1,
                                                    ush* __restrict__ h1) {
    __shared__ float acc[BNODES * S1];
    int b = blockIdx.x, t = threadIdx.x;
    for (int i = t; i < BNODES * S1; i += 512) acc[i] = 0.f;
    __syncthreads();
    int e0 = b * BCAP, e1 = bcur[b];
    int slot = t >> 3, fg = t & 7;          // 64 edge slots x 8 fgroups (8 feats each)
    for (int i = e0 + slot; i < e1; i += 64) {
        unsigned u = tmp[i];
        int s = (int)(u >> 8);
        int dl = (int)(u & 255);
        uint4 v = *(const uint4*)&Hs[s * DH + fg * 8];
        float* a = &acc[dl * S1 + fg * 8];
        atomicAdd(&a[0], bflo(v.x)); atomicAdd(&a[1], bfhi(v.x));
        atomicAdd(&a[2], bflo(v.y)); atomicAdd(&a[3], bfhi(v.y));
        atomicAdd(&a[4], bflo(v.z)); atomicAdd(&a[5], bfhi(v.z));
        atomicAdd(&a[6], bflo(v.w)); atomicAdd(&a[7], bfhi(v.w));
    }
    __syncthreads();
    // finish: 512 threads = 256 nodes x 2 halves (32 feats each)
    int nl = t >> 1, f0 = (t & 1) * 32;
    int node = (b << BSH) + nl;
    if (node >= NN) return;
    float dv = dinv[node];
    const float* ar = &acc[nl * S1 + f0];
    ushort4 o[4];
#pragma unroll
    for (int g = 0; g < 4; g++) {
        uint4 su = *(const uint4*)&Hs[node * DH + f0 + g * 8];
        float4 ba = *(const float4*)&b1[f0 + g * 8];
        float4 bb = *(const float4*)&b1[f0 + g * 8 + 4];
        ushort4 oa;
        oa.x = f2bf(fmaxf(dv * (ar[g * 8 + 0] + bflo(su.x)) + ba.x, 0.f));
        oa.y = f2bf(fmaxf(dv * (ar[g * 8 + 1] + bfhi(su.x)) + ba.y, 0.f));
        oa.z = f2bf(fmaxf(dv * (ar[g * 8 + 2] + bflo(su.y)) + ba.z, 0.f));
        oa.w = f2bf(fmaxf(dv * (ar[g * 8 + 3] + bfhi(su.y)) + ba.w, 0.f));
        ushort4 ob;
        ob.x = f2bf(fmaxf(dv * (ar[g * 8 + 4] + bflo(su.z)) + bb.x, 0.f));
        ob.y = f2bf(fmaxf(dv * (ar[g * 8 + 5] + bfhi(su.z)) + bb.y, 0.f));
        ob.z = f2bf(fmaxf(dv * (ar[g * 8 + 6] + bflo(su.w)) + bb.z, 0.f));
        ob.w = f2bf(fmaxf(dv * (ar[g * 8 + 7] + bfhi(su.w)) + bb.w, 0.f));
        o[g] = make_ushort4(oa.x, oa.y, oa.z, oa.w);
        // pack second half into the same 16B store stream
        *(ushort4*)&h1[node * DH + f0 + g * 8] = oa;
        *(ushort4*)&h1[node * DH + f0 + g * 8 + 4] = ob;
    }
    (void)o;
}

// ---------------- scat2: block-per-bucket LDS scatter, F=32, + fc score ---------------
#define S2 33
__global__ __launch_bounds__(512) void scat2_kernel(const unsigned* __restrict__ tmp,
                                                    const int* __restrict__ bcur,
                                                    const float* __restrict__ dinv,
                                                    const ush* __restrict__ Hs,
                                                    const float* __restrict__ b2,
                                                    const float* __restrict__ fcw,
                                                    const float* __restrict__ fcb,
                                                    float* __restrict__ h2,
                                                    float* __restrict__ scores) {
    __shared__ float acc[BNODES * S2];
    int b = blockIdx.x, t = threadIdx.x;
    for (int i = t; i < BNODES * S2; i += 512) acc[i] = 0.f;
    __syncthreads();
    int e0 = b * BCAP, e1 = bcur[b];
    int slot = t >> 2, fg = t & 3;          // 128 edge slots x 4 fgroups (8 feats each)
    for (int i = e0 + slot; i < e1; i += 128) {
        unsigned u = tmp[i];
        int s = (int)(u >> 8);
        int dl = (int)(u & 255);
        uint4 v = *(const uint4*)&Hs[s * DOUT + fg * 8];
        float* a = &acc[dl * S2 + fg * 8];
        atomicAdd(&a[0], bflo(v.x)); atomicAdd(&a[1], bfhi(v.x));
        atomicAdd(&a[2], bflo(v.y)); atomicAdd(&a[3], bfhi(v.y));
        atomicAdd(&a[4], bflo(v.z)); atomicAdd(&a[5], bfhi(v.z));
        atomicAdd(&a[6], bflo(v.w)); atomicAdd(&a[7], bfhi(v.w));
    }
    __syncthreads();
    // finish: first 256 threads = 1 node each (32 feats)
    if (t >= BNODES) return;
    int node = (b << BSH) + t;
    if (node >= NN) return;
    float dv = dinv[node];
    const float* ar = &acc[t * S2];
    float sv = 0.f;
#pragma unroll
    for (int g = 0; g < 4; g++) {
        uint4 su = *(const uint4*)&Hs[node * DOUT + g * 8];
        float4 ba = *(const float4*)&b2[g * 8];
        float4 bb = *(const float4*)&b2[g * 8 + 4];
        float4 fa = *(const float4*)&fcw[g * 8];
        float4 fb = *(const float4*)&fcw[g * 8 + 4];
        float4 o0, o1;
        o0.x = fmaxf(dv * (ar[g * 8 + 0] + bflo(su.x)) + ba.x, 0.f);
        o0.y = fmaxf(dv * (ar[g * 8 + 1] + bfhi(su.x)) + ba.y, 0.f);
        o0.z = fmaxf(dv * (ar[g * 8 + 2] + bflo(su.y)) + ba.z, 0.f);
        o0.w = fmaxf(dv * (ar[g * 8 + 3] + bfhi(su.y)) + ba.w, 0.f);
        o1.x = fmaxf(dv * (ar[g * 8 + 4] + bflo(su.z)) + bb.x, 0.f);
        o1.y = fmaxf(dv * (ar[g * 8 + 5] + bfhi(su.z)) + bb.y, 0.f);
        o1.z = fmaxf(dv * (ar[g * 8 + 6] + bflo(su.w)) + bb.z, 0.f);
        o1.w = fmaxf(dv * (ar[g * 8 + 7] + bfhi(su.w)) + bb.w, 0.f);
        *(float4*)&h2[node * DOUT + g * 8] = o0;
        *(float4*)&h2[node * DOUT + g * 8 + 4] = o1;
        sv += o0.x * fa.x + o0.y * fa.y + o0.z * fa.z + o0.w * fa.w
            + o1.x * fb.x + o1.y * fb.y + o1.z * fb.z + o1.w * fb.w;
    }
    scores[node] = sv + fcb[0];
}

extern "C" void kernel_launch(void* const* d_in, const int* in_sizes, int n_in,
                              void* d_out, int out_size, void* d_ws, size_t ws_size,
                              hipStream_t stream) {
    const float* x   = (const float*)d_in[0];
    const int*   ei  = (const int*)d_in[1];
    const float* W1  = (const float*)d_in[2];
    const float* b1  = (const float*)d_in[3];
    const float* W2  = (const float*)d_in[4];
    const float* b2  = (const float*)d_in[5];
    const float* fcw = (const float*)d_in[6];
    const float* fcb = (const float*)d_in[7];
    const int* src = ei;
    const int* dst = ei + EE;

    float* ws = (float*)d_ws;
    float* dinv    = ws;                          // NN f
    int*   bcur    = (int*)(ws + 100352);         // NBUCK
    unsigned* tmp  = (unsigned*)(ws + 100864);    // NBUCK*BCAP u32, ends @ 1,902,592
    ush*   Hs1     = (ush*)(ws + 1902592);        // NN*64 bf16 (3.2M f)
    ush*   Hs2     = (ush*)(ws + 5102592);        // NN*32 bf16 (1.6M f)
    ush*   h1      = (ush*)(ws + 6702592);        // NN*64 bf16 (3.2M f), ends @ 39.6 MB

    float* out    = (float*)d_out;
    float* scores = out;          // NN
    float* h2     = out + NN;     // NN*32

    const int T = 256;
    // bucket binning (no csr): init, binA (bucket-grouped edges), binC (deg->dinv)
    init_bcur_kernel<<<2, 256, 0, stream>>>(bcur);
    binA_kernel<<<NCHUNK, T, 0, stream>>>(src, dst, bcur, tmp);
    binC_kernel<<<NBUCK, T, 0, stream>>>(tmp, bcur, dinv);
    // layer 1: Hs1 = bf16((x@W1)*dinv)   [MFMA]
    gemm_mfma_kernel<DIN, DH, float><<<(NN + 127) / 128, T, 0, stream>>>(x, W1, dinv, Hs1);
    scat1_kernel<<<NBUCK, 512, 0, stream>>>(tmp, bcur, dinv, Hs1, b1, h1);
    // layer 2: Hs2 = bf16((h1@W2)*dinv)  [MFMA, bf16 input]
    gemm_mfma_kernel<DH, DOUT, ush><<<(NN + 127) / 128, T, 0, stream>>>(h1, W2, dinv, Hs2);
    scat2_kernel<<<NBUCK, 512, 0, stream>>>(tmp, bcur, dinv, Hs2, b2, fcw, fcb, h2, scores);
}

// Round 14
// 221.144 us; speedup vs baseline: 5.3188x; 5.3188x over previous
//
#include <hip/hip_runtime.h>

#define NN 100000
#define EE 1600000
#define DIN 128
#define DH 64
#define DOUT 32

#define BSH 8                      // bucket = dst >> 8  (256 nodes/bucket)
#define BNODES 256
#define NBUCK ((NN + BNODES - 1) / BNODES)   // 391
#define BCAP 4608                  // fixed bucket capacity (mean 4096 + 8 sigma)
#define CHUNK 4096                 // edges per Pass-A workgroup
#define NCHUNK ((EE + CHUNK - 1) / CHUNK)    // 391

typedef unsigned short ush;
typedef __attribute__((ext_vector_type(8))) short bf16x8;
typedef __attribute__((ext_vector_type(4))) float f32x4;

__device__ __forceinline__ float bflo(unsigned u) {
    union { unsigned u; float f; } c; c.u = u << 16; return c.f;
}
__device__ __forceinline__ float bfhi(unsigned u) {
    union { unsigned u; float f; } c; c.u = u & 0xffff0000u; return c.f;
}
__device__ __forceinline__ ush f2bf(float f) {
    union { float f; unsigned u; } c; c.f = f;
    unsigned r = c.u + 0x7fff + ((c.u >> 16) & 1);   // round-to-nearest-even
    return (ush)(r >> 16);
}

// ---------------- init bucket cursors to fixed bases ----------------
__global__ void init_bcur_kernel(int* __restrict__ bcur) {
    int i = blockIdx.x * 256 + threadIdx.x;
    if (i < NBUCK) bcur[i] = i * BCAP;
}

// ---------------- Pass A: bin edges into fixed-capacity buckets (packed (src<<8)|dstlow)
__global__ __launch_bounds__(256) void binA_kernel(const int* __restrict__ src,
                                                   const int* __restrict__ dst,
                                                   int* __restrict__ bcur,
                                                   unsigned* __restrict__ tmp) {
    __shared__ int hist[NBUCK];
    __shared__ int scn[NBUCK];      // exclusive scan (staging base per bucket)
    __shared__ int cur[NBUCK];      // staging cursor
    __shared__ int gb[NBUCK];       // global base - scn  (addr = gb[b] + lp)
    __shared__ int s2[256];
    __shared__ unsigned staged[CHUNK];
    __shared__ int gaddr[CHUNK];
    int t = threadIdx.x;
    for (int i = t; i < NBUCK; i += 256) hist[i] = 0;
    __syncthreads();
    int e0 = blockIdx.x * CHUNK;
    int nE = min(CHUNK, EE - e0);

    int my_e[16], my_bk[16];
#pragma unroll
    for (int k = 0; k < 16; k++) {
        int li = t + k * 256;
        bool ok = li < nE;
        int idx = ok ? (e0 + li) : e0;
        int d = dst[idx];
        int s = src[idx];
        int b = d >> BSH;
        my_e[k] = (s << 8) | (d & 255);
        my_bk[k] = ok ? b : -1;
        if (ok) atomicAdd(&hist[b], 1);
    }
    __syncthreads();
    int a0 = (2 * t < NBUCK) ? hist[2 * t] : 0;
    int a1 = (2 * t + 1 < NBUCK) ? hist[2 * t + 1] : 0;
    s2[t] = a0 + a1;
    __syncthreads();
    for (int off = 1; off < 256; off <<= 1) {
        int x = (t >= off) ? s2[t - off] : 0;
        __syncthreads();
        s2[t] += x;
        __syncthreads();
    }
    int excl = s2[t] - a0 - a1;
    if (2 * t < NBUCK)     { scn[2 * t] = excl;          cur[2 * t] = excl; }
    if (2 * t + 1 < NBUCK) { scn[2 * t + 1] = excl + a0; cur[2 * t + 1] = excl + a0; }
    __syncthreads();
    for (int i = t; i < NBUCK; i += 256) {
        int h = hist[i];
        if (h) gb[i] = atomicAdd(&bcur[i], h) - scn[i];
    }
    __syncthreads();
#pragma unroll
    for (int k = 0; k < 16; k++) {
        int b = my_bk[k];
        if (b >= 0) {
            int lp = atomicAdd(&cur[b], 1);
            staged[lp] = (unsigned)my_e[k];
            gaddr[lp] = gb[b] + lp;
        }
    }
    __syncthreads();
    for (int i = t; i < nE; i += 256)
        tmp[gaddr[i]] = staged[i];
}

// ---------------- Pass B: per-bucket node histogram + scan -> offs/ends/dinv/csr -------
__global__ __launch_bounds__(256) void binB_kernel(const unsigned* __restrict__ tmp,
                                                   const int* __restrict__ bcur,
                                                   int* __restrict__ csr,
                                                   int* __restrict__ offs,
                                                   int* __restrict__ ends,
                                                   float* __restrict__ dinv) {
    __shared__ int hist[BNODES], cur[BNODES], sc[BNODES];
    int b = blockIdx.x, t = threadIdx.x;
    int e0 = b * BCAP, e1 = bcur[b];
    hist[t] = 0;
    __syncthreads();
    for (int i = e0 + t; i < e1; i += 256) atomicAdd(&hist[tmp[i] & 255], 1);
    __syncthreads();
    int v = hist[t];
    sc[t] = v;
    __syncthreads();
    for (int off = 1; off < 256; off <<= 1) {
        int x = (t >= off) ? sc[t - off] : 0;
        __syncthreads();
        sc[t] += x;
        __syncthreads();
    }
    int excl = sc[t] - v;
    cur[t] = e0 + excl;
    int node = (b << BSH) + t;
    if (node < NN) {
        offs[node] = e0 + excl;
        ends[node] = e0 + excl + v;
        dinv[node] = 1.0f / sqrtf((float)v + 1.0f);
    }
    __syncthreads();
    for (int i = e0 + t; i < e1; i += 256) {
        unsigned u = tmp[i];
        int pos = atomicAdd(&cur[u & 255], 1);
        csr[pos] = (int)(u >> 8);
    }
}

// ---------------- MFMA GEMM + dinv-scale, bf16 out: Y = bf16((X@W)*dinv) -------------
template <int K, int NC, typename XT>
__global__ __launch_bounds__(256) void gemm_mfma_kernel(const XT* __restrict__ X,
                                                        const float* __restrict__ W,
                                                        const float* __restrict__ dinv,
                                                        ush* __restrict__ Y) {
    constexpr int GROWS = 128;
    constexpr int KP = K + 8;            // pad: row stride odd multiple of 16B
    constexpr int NKC = K / 32;          // k-chunks
    constexpr int NCT = NC / 16;         // col tiles
    __shared__ __align__(16) ush Xl[GROWS * KP];
    __shared__ __align__(16) ush Wt[NC * KP];
    const int t = threadIdx.x;
    const int row0 = blockIdx.x * GROWS;

    if constexpr (sizeof(XT) == 4) {
        for (int i = t; i < GROWS * (K / 4); i += 256) {
            int r = i / (K / 4), c4 = i % (K / 4);
            int row = row0 + r;
            float4 v = make_float4(0.f, 0.f, 0.f, 0.f);
            if (row < NN) v = *(const float4*)&X[(size_t)row * K + c4 * 4];
            ushort4 o;
            o.x = f2bf(v.x); o.y = f2bf(v.y); o.z = f2bf(v.z); o.w = f2bf(v.w);
            *(ushort4*)&Xl[r * KP + c4 * 4] = o;
        }
    } else {
        for (int i = t; i < GROWS * (K / 8); i += 256) {
            int r = i / (K / 8), c8 = i % (K / 8);
            int row = row0 + r;
            uint4 v = make_uint4(0, 0, 0, 0);
            if (row < NN) v = *(const uint4*)&X[(size_t)row * K + c8 * 8];
            *(uint4*)&Xl[r * KP + c8 * 8] = v;
        }
    }
    for (int i = t; i < K * (NC / 4); i += 256) {
        int k = i / (NC / 4), n4 = i % (NC / 4);
        float4 v = *(const float4*)&W[k * NC + n4 * 4];
        Wt[(n4 * 4 + 0) * KP + k] = f2bf(v.x);
        Wt[(n4 * 4 + 1) * KP + k] = f2bf(v.y);
        Wt[(n4 * 4 + 2) * KP + k] = f2bf(v.z);
        Wt[(n4 * 4 + 3) * KP + k] = f2bf(v.w);
    }
    __syncthreads();

    const int wave = t >> 6, lane = t & 63;
    const int m = lane & 15, quad = lane >> 4;
    const int wrow = wave * 32;

    f32x4 acc[2][NCT];
#pragma unroll
    for (int rt = 0; rt < 2; rt++)
#pragma unroll
        for (int ct = 0; ct < NCT; ct++) acc[rt][ct] = (f32x4){0.f, 0.f, 0.f, 0.f};

#pragma unroll
    for (int kc = 0; kc < NKC; kc++) {
        int koff = kc * 32 + quad * 8;
        bf16x8 b[NCT];
#pragma unroll
        for (int ct = 0; ct < NCT; ct++)
            b[ct] = *(const bf16x8*)&Wt[(ct * 16 + m) * KP + koff];
#pragma unroll
        for (int rt = 0; rt < 2; rt++) {
            bf16x8 a = *(const bf16x8*)&Xl[(wrow + rt * 16 + m) * KP + koff];
#pragma unroll
            for (int ct = 0; ct < NCT; ct++)
                acc[rt][ct] = __builtin_amdgcn_mfma_f32_16x16x32_bf16(a, b[ct], acc[rt][ct], 0, 0, 0);
        }
    }
#pragma unroll
    for (int rt = 0; rt < 2; rt++) {
#pragma unroll
        for (int reg = 0; reg < 4; reg++) {
            int row = row0 + wrow + rt * 16 + quad * 4 + reg;
            if (row < NN) {
                float s = dinv[row];
#pragma unroll
                for (int ct = 0; ct < NCT; ct++)
                    Y[(size_t)row * NC + ct * 16 + m] = f2bf(acc[rt][ct][reg] * s);
            }
        }
    }
}

#define ACC8(u4)                                      \
    acc0 += bflo(u4.x); acc1 += bfhi(u4.x);           \
    acc2 += bflo(u4.y); acc3 += bfhi(u4.y);           \
    acc4 += bflo(u4.z); acc5 += bfhi(u4.z);           \
    acc6 += bflo(u4.w); acc7 += bfhi(u4.w);

// ---------------- gather1 (F=64 bf16): 2 nodes/wave, 4 slots x 8 fgroups, 4-deep -------
// h1 = bf16(relu(dv*(sum Hs1[s] + Hs1[node]) + b1))
__global__ __launch_bounds__(256) void gather1_kernel(const int* __restrict__ offs,
                                                      const int* __restrict__ ends,
                                                      const float* __restrict__ dinv,
                                                      const ush* __restrict__ Hs,
                                                      const int* __restrict__ csr,
                                                      const float* __restrict__ b1,
                                                      ush* __restrict__ h1) {
    int wid = (blockIdx.x * 256 + threadIdx.x) >> 6;
    int lane = threadIdx.x & 63;
    int node = wid * 2 + (lane >> 5);
    if (node >= NN) return;
    int l = lane & 31;
    int es = l >> 3;                     // 4 edge slots (stride 4)
    int fg = l & 7;                      // 8 fgroups x 8 bf16 = 16 B
    int start = offs[node], end = ends[node];
    float dv = dinv[node];                                   // hoisted: in flight during loop
    uint4 su = *(const uint4*)&Hs[node * DH + fg * 8];       // hoisted self-row
    float acc0 = 0.f, acc1 = 0.f, acc2 = 0.f, acc3 = 0.f;
    float acc4 = 0.f, acc5 = 0.f, acc6 = 0.f, acc7 = 0.f;
    int k = start + es;
    for (; k + 12 < end; k += 16) {      // 4 independent rows in flight per lane
        int s0 = csr[k], s1 = csr[k + 4], s2 = csr[k + 8], s3 = csr[k + 12];
        uint4 u0 = *(const uint4*)&Hs[s0 * DH + fg * 8];
        uint4 u1 = *(const uint4*)&Hs[s1 * DH + fg * 8];
        uint4 u2 = *(const uint4*)&Hs[s2 * DH + fg * 8];
        uint4 u3 = *(const uint4*)&Hs[s3 * DH + fg * 8];
        ACC8(u0) ACC8(u1) ACC8(u2) ACC8(u3)
    }
    for (; k < end; k += 4) {
        int s = csr[k];
        uint4 u = *(const uint4*)&Hs[s * DH + fg * 8];
        ACC8(u)
    }
    // reduce over es (lanes differ in bits 3,4 of the 32-lane half)
#pragma unroll
    for (int m = 8; m <= 16; m <<= 1) {
        acc0 += __shfl_xor(acc0, m); acc1 += __shfl_xor(acc1, m);
        acc2 += __shfl_xor(acc2, m); acc3 += __shfl_xor(acc3, m);
        acc4 += __shfl_xor(acc4, m); acc5 += __shfl_xor(acc5, m);
        acc6 += __shfl_xor(acc6, m); acc7 += __shfl_xor(acc7, m);
    }
    float4 ba = *(const float4*)&b1[fg * 8];
    float4 bb = *(const float4*)&b1[fg * 8 + 4];
    if (es == 0) {
        ushort4 o0, o1;
        o0.x = f2bf(fmaxf(dv * (acc0 + bflo(su.x)) + ba.x, 0.f));
        o0.y = f2bf(fmaxf(dv * (acc1 + bfhi(su.x)) + ba.y, 0.f));
        o0.z = f2bf(fmaxf(dv * (acc2 + bflo(su.y)) + ba.z, 0.f));
        o0.w = f2bf(fmaxf(dv * (acc3 + bfhi(su.y)) + ba.w, 0.f));
        o1.x = f2bf(fmaxf(dv * (acc4 + bflo(su.z)) + bb.x, 0.f));
        o1.y = f2bf(fmaxf(dv * (acc5 + bfhi(su.z)) + bb.y, 0.f));
        o1.z = f2bf(fmaxf(dv * (acc6 + bflo(su.w)) + bb.z, 0.f));
        o1.w = f2bf(fmaxf(dv * (acc7 + bfhi(su.w)) + bb.w, 0.f));
        *(ushort4*)&h1[node * DH + fg * 8] = o0;
        *(ushort4*)&h1[node * DH + fg * 8 + 4] = o1;
    }
}

// ---------------- gather2 (F=32 bf16): 2 nodes/wave, 8 slots x 4 fgroups, 2-deep + fc --
__global__ __launch_bounds__(256) void gather2_kernel(const int* __restrict__ offs,
                                                      const int* __restrict__ ends,
                                                      const float* __restrict__ dinv,
                                                      const ush* __restrict__ Hs,
                                                      const int* __restrict__ csr,
                                                      const float* __restrict__ b2,
                                                      const float* __restrict__ fcw,
                                                      const float* __restrict__ fcb,
                                                      float* __restrict__ h2,
                                                      float* __restrict__ scores) {
    int wid = (blockIdx.x * 256 + threadIdx.x) >> 6;
    int lane = threadIdx.x & 63;
    int node = wid * 2 + (lane >> 5);
    if (node >= NN) return;
    int l = lane & 31;
    int es = l >> 2;                     // 8 edge slots (stride 8)
    int fg = l & 3;                      // 4 fgroups x 8 bf16 = 16 B
    int start = offs[node], end = ends[node];
    float dv = dinv[node];                                   // hoisted
    uint4 su = *(const uint4*)&Hs[node * DOUT + fg * 8];     // hoisted self-row
    float acc0 = 0.f, acc1 = 0.f, acc2 = 0.f, acc3 = 0.f;
    float acc4 = 0.f, acc5 = 0.f, acc6 = 0.f, acc7 = 0.f;
    int k = start + es;
    for (; k + 8 < end; k += 16) {       // 2 independent rows in flight per lane
        int s0 = csr[k], s1 = csr[k + 8];
        uint4 u0 = *(const uint4*)&Hs[s0 * DOUT + fg * 8];
        uint4 u1 = *(const uint4*)&Hs[s1 * DOUT + fg * 8];
        ACC8(u0) ACC8(u1)
    }
    for (; k < end; k += 8) {
        int s = csr[k];
        uint4 u = *(const uint4*)&Hs[s * DOUT + fg * 8];
        ACC8(u)
    }
    // reduce over es (lanes differ in bits 2,3,4 of the 32-lane half)
#pragma unroll
    for (int m = 4; m <= 16; m <<= 1) {
        acc0 += __shfl_xor(acc0, m); acc1 += __shfl_xor(acc1, m);
        acc2 += __shfl_xor(acc2, m); acc3 += __shfl_xor(acc3, m);
        acc4 += __shfl_xor(acc4, m); acc5 += __shfl_xor(acc5, m);
        acc6 += __shfl_xor(acc6, m); acc7 += __shfl_xor(acc7, m);
    }
    float4 ba = *(const float4*)&b2[fg * 8];
    float4 bb = *(const float4*)&b2[fg * 8 + 4];
    float4 o0, o1;
    o0.x = fmaxf(dv * (acc0 + bflo(su.x)) + ba.x, 0.f);
    o0.y = fmaxf(dv * (acc1 + bfhi(su.x)) + ba.y, 0.f);
    o0.z = fmaxf(dv * (acc2 + bflo(su.y)) + ba.z, 0.f);
    o0.w = fmaxf(dv * (acc3 + bfhi(su.y)) + ba.w, 0.f);
    o1.x = fmaxf(dv * (acc4 + bflo(su.z)) + bb.x, 0.f);
    o1.y = fmaxf(dv * (acc5 + bfhi(su.z)) + bb.y, 0.f);
    o1.z = fmaxf(dv * (acc6 + bflo(su.w)) + bb.z, 0.f);
    o1.w = fmaxf(dv * (acc7 + bfhi(su.w)) + bb.w, 0.f);
    if (es == 0) {
        *(float4*)&h2[node * DOUT + fg * 8] = o0;
        *(float4*)&h2[node * DOUT + fg * 8 + 4] = o1;
    }
    float4 fa = *(const float4*)&fcw[fg * 8];
    float4 fb = *(const float4*)&fcw[fg * 8 + 4];
    float sv = o0.x * fa.x + o0.y * fa.y + o0.z * fa.z + o0.w * fa.w
             + o1.x * fb.x + o1.y * fb.y + o1.z * fb.z + o1.w * fb.w;
    sv += __shfl_xor(sv, 1); sv += __shfl_xor(sv, 2);
    if (l == 0) scores[node] = sv + fcb[0];
}

extern "C" void kernel_launch(void* const* d_in, const int* in_sizes, int n_in,
                              void* d_out, int out_size, void* d_ws, size_t ws_size,
                              hipStream_t stream) {
    const float* x   = (const float*)d_in[0];
    const int*   ei  = (const int*)d_in[1];
    const float* W1  = (const float*)d_in[2];
    const float* b1  = (const float*)d_in[3];
    const float* W2  = (const float*)d_in[4];
    const float* b2  = (const float*)d_in[5];
    const float* fcw = (const float*)d_in[6];
    const float* fcb = (const float*)d_in[7];
    const int* src = ei;
    const int* dst = ei + EE;

    float* ws = (float*)d_ws;
    float* dinv    = ws;                          // NN f
    int*   offs    = (int*)(ws + 100352);         // NN
    int*   ends    = (int*)(ws + 200704);         // NN
    int*   bcur    = (int*)(ws + 301056);         // NBUCK
    int*   csr     = (int*)(ws + 301568);         // NBUCK*BCAP
    unsigned* tmp  = (unsigned*)(ws + 2103296);   // NBUCK*BCAP
    ush*   Hs1     = (ush*)(ws + 3905024);        // NN*64 bf16
    ush*   Hs2     = (ush*)(ws + 7105024);        // NN*32 bf16
    ush*   h1      = (ush*)(ws + 8705024);        // NN*64 bf16

    float* out    = (float*)d_out;
    float* scores = out;          // NN
    float* h2     = out + NN;     // NN*32

    const int T = 256;
    // CSR build (fixed-capacity bucket binning)
    init_bcur_kernel<<<2, 256, 0, stream>>>(bcur);
    binA_kernel<<<NCHUNK, T, 0, stream>>>(src, dst, bcur, tmp);
    binB_kernel<<<NBUCK, T, 0, stream>>>(tmp, bcur, csr, offs, ends, dinv);
    // layer 1: Hs1 = bf16((x@W1)*dinv)   [MFMA]
    gemm_mfma_kernel<DIN, DH, float><<<(NN + 127) / 128, T, 0, stream>>>(x, W1, dinv, Hs1);
    gather1_kernel<<<(NN / 2 * 64 + T - 1) / T, T, 0, stream>>>(offs, ends, dinv, Hs1, csr, b1, h1);
    // layer 2: Hs2 = bf16((h1@W2)*dinv)  [MFMA, bf16 input]
    gemm_mfma_kernel<DH, DOUT, ush><<<(NN + 127) / 128, T, 0, stream>>>(h1, W2, dinv, Hs2);
    gather2_kernel<<<(NN / 2 * 64 + T - 1) / T, T, 0, stream>>>(offs, ends, dinv, Hs2, csr, b2, fcw, fcb, h2, scores);
}